// Round 4
// baseline (5777.642 us; speedup 1.0000x reference)
//
#include <hip/hip_runtime.h>
#include <math.h>

// ESN: B=64, T=2048, I=25, R=512, O=50, alpha=0.5
// 256 blocks x 512 threads; block=(g,b): b=blk&63, g=blk>>6 owns rows
// [g*128,(g+1)*128). W slice [128x512] fp32 in regs. Seqlock-tagged h pairs
// {h, tag=t+1} (8B single-copy atomic), double-buffered by step parity.
// R12 = R10 byte-for-byte EXCEPT the publish store:
//   store_ic8 (sc0 sc1 only)  ->  store_fast_safe (sc0, THEN sc0 sc1).
// Hypothesis: the sc0 sc1 write-through store does not leave the L2 line
// peer-observable, so R8/R10's sc0 fast path silently dies at t=1 (64-try
// watchdog ~16kcy one-time, invisible) and every step polls via IC
// (~900cy RT, often 2 rounds) -> step 3240cy with only ~1600cy VALU, and
// FETCH residual ~190MB = poll misses. The sc0-first store dirties the
// shared per-XCD L2 -> peer sc0 polls hit at ~250cy RT. The sc0 sc1
// second store (same addr, same payload, idempotent) preserves the
// R5-proven device-visible copy for the sc1 fallback -> cannot hang.
// R11's failure was the split issue/wait asm (in-flight dest regs copied
// by regalloc before waitcnt) -- that change is reverted entirely.
// ws usage: EXACTLY 512 KB (Hf only), same as passing R5/R8/R10.

typedef float v2f __attribute__((ext_vector_type(2)));
typedef float v4f __attribute__((ext_vector_type(4)));

template<int CTRL>
__device__ __forceinline__ float dpp_add(float x) {
    int y = __builtin_amdgcn_update_dpp(0, __float_as_int(x), CTRL, 0xF, 0xF, false);
    return x + __int_as_float(y);
}
// 0xB1 quad_perm[1,0,3,2], 0x4E quad_perm[2,3,0,1], 0x124 row_ror:4,
// 0x128 row_ror:8, 0x142 row_bcast15

// sc0 store (fast local-L2 visibility) then sc0 sc1 write-through (safety).
__device__ __forceinline__ void store_fast_safe(float* p, float h, int tag) {
    v2f v; v[0] = h; v[1] = __int_as_float(tag);
    asm volatile("global_store_dwordx2 %0, %1, off sc0\n\t"
                 "global_store_dwordx2 %0, %1, off sc0 sc1"
                 :: "v"(p), "v"(v) : "memory");
}
// 3 tagged 16B loads + wait in ONE asm block (R5-proven codegen shape)
__device__ __forceinline__ void load3_ic(const float* p0, const float* p1,
                                         const float* p2, v4f& a, v4f& b, v4f& c) {
    asm volatile("global_load_dwordx4 %0, %3, off sc0 sc1\n\t"
                 "global_load_dwordx4 %1, %4, off sc0 sc1\n\t"
                 "global_load_dwordx4 %2, %5, off sc0 sc1\n\t"
                 "s_waitcnt vmcnt(0)"
                 : "=&v"(a), "=&v"(b), "=&v"(c)
                 : "v"(p0), "v"(p1), "v"(p2) : "memory");
}
__device__ __forceinline__ void load3_l2(const float* p0, const float* p1,
                                         const float* p2, v4f& a, v4f& b, v4f& c) {
    asm volatile("global_load_dwordx4 %0, %3, off sc0\n\t"
                 "global_load_dwordx4 %1, %4, off sc0\n\t"
                 "global_load_dwordx4 %2, %5, off sc0\n\t"
                 "s_waitcnt vmcnt(0)"
                 : "=&v"(a), "=&v"(b), "=&v"(c)
                 : "v"(p0), "v"(p1), "v"(p2) : "memory");
}

__device__ __forceinline__ int permidx(int c) {
    return (c >> 7) * 128 + (c & 31) * 4 + ((c >> 5) & 3);
}

#define TAGS_BAD (__any((__float_as_int(d0.y) != want) | (__float_as_int(d0.w) != want) | \
                        (__float_as_int(d1.y) != want) | (__float_as_int(d1.w) != want) | \
                        (__float_as_int(d2.y) != want) | (__float_as_int(d2.w) != want)))

__global__ void __launch_bounds__(512, 2)
esn_kernel(const float* __restrict__ x, const float* __restrict__ Win,
           const float* __restrict__ W, const float* __restrict__ Wout,
           float* __restrict__ out, float* __restrict__ Hf)
{
    const int b    = blockIdx.x & 63;
    const int g    = blockIdx.x >> 6;
    const int tid  = threadIdx.x;
    const int rt   = tid >> 5;      // row-tile 0..15 (8 rows each)
    const int ct   = tid & 31;      // col phase
    const int lane = tid & 63;
    const int wv   = tid >> 6;      // wave 0..7
    const int hw   = rt & 1;

    __shared__ __align__(16) float hperm[2][512];

    // ---- W slice -> registers
    v2f Wreg[64];
    {
        const int i0 = g*128 + rt*8;
        #pragma unroll
        for (int r = 0; r < 4; ++r)
        #pragma unroll
        for (int q = 0; q < 4; ++q) {
            const float* wp = W + (r*128 + q*32 + ct);
            #pragma unroll
            for (int p = 0; p < 4; ++p) {
                v2f w;
                w[0] = wp[(size_t)(i0 + 2*p    ) * 512];
                w[1] = wp[(size_t)(i0 + 2*p + 1) * 512];
                Wreg[(r*4+q)*4 + p] = w;
            }
        }
    }

    // ---- Win row for this lane's finalize row i0+(ct&7)
    const int myrow = g*128 + rt*8 + (ct & 7);
    float WinR[25];
    #pragma unroll
    for (int k = 0; k < 25; ++k) WinR[k] = Win[myrow*25 + k];

    // ---- Wout fragment
    const int obase = g*13;
    const int ocnt  = (g == 3) ? 11 : 13;
    const int oloc  = 2*wv + hw;
    const bool ovalid = (oloc < ocnt);
    const int oidx  = obase + (ovalid ? oloc : 0);
    float WoutR[16];
    #pragma unroll
    for (int r = 0; r < 4; ++r)
    #pragma unroll
    for (int q = 0; q < 4; ++q)
        WoutR[r*4+q] = ovalid ? Wout[oidx*512 + r*128 + q*32 + ct] : 0.f;

    hperm[0][tid] = 0.f;        // h_0 = 0
    float holdv = 0.f;
    const bool fin = (ct >= 16) & (ct < 24);

    const float* xrow = x   + (size_t)b * 2048 * 25;
    float*       orow = out + (size_t)b * 2048 * 50;
    float* HfB0 = Hf + (size_t)b * 1024;              // par-0 base (pairs)
    const int s0 = (g+1)&3, s1 = (g+2)&3, s2 = (g+3)&3;

    bool fast = true;           // sticky fast-path flag (comm wave only)

    __syncthreads();

    // u for t=0
    float u = 0.f;
    #pragma unroll
    for (int k = 0; k < 25; ++k) u = fmaf(WinR[k], xrow[k], u);

    for (int t = 0; t < 2048; ++t) {
        const int par  = t & 1;
        const int npar = par ^ 1;
        const int want = t + 1;
        float* HfN = HfB0 + (size_t)npar * 64 * 1024;

        // ---- matvec on h_t + fused output-projection partial
        v2f acc0 = {0.f,0.f}, acc1 = {0.f,0.f}, acc2 = {0.f,0.f}, acc3 = {0.f,0.f};
        float op = 0.f;
        #pragma unroll
        for (int r = 0; r < 4; ++r) {
            v4f hv = *(const v4f*)&hperm[par][r*128 + ct*4];
            #pragma unroll
            for (int q = 0; q < 4; ++q) {
                const float hs = hv[q];
                op = fmaf(WoutR[r*4+q], hs, op);
                v2f hh = {hs, hs};
                acc0 = __builtin_elementwise_fma(Wreg[(r*4+q)*4+0], hh, acc0);
                acc1 = __builtin_elementwise_fma(Wreg[(r*4+q)*4+1], hh, acc1);
                acc2 = __builtin_elementwise_fma(Wreg[(r*4+q)*4+2], hh, acc2);
                acc3 = __builtin_elementwise_fma(Wreg[(r*4+q)*4+3], hh, acc3);
            }
        }

        // ---- FULL 32-lane reduce of 8 row partials (totals land in lanes 16..31)
        float ar[8] = {acc0[0],acc0[1],acc1[0],acc1[1],acc2[0],acc2[1],acc3[0],acc3[1]};
        #pragma unroll
        for (int j = 0; j < 8; ++j) {
            ar[j] = dpp_add<0xB1>(ar[j]);
            ar[j] = dpp_add<0x4E>(ar[j]);
            ar[j] = dpp_add<0x124>(ar[j]);
            ar[j] = dpp_add<0x128>(ar[j]);
            ar[j] = dpp_add<0x142>(ar[j]);
        }

        // ---- finalize rows i0+(ct&7) (lanes ct in [16,24)), publish ASAP
        if (fin) {
            const int j = ct & 7;
            float y = ar[0];
            if (j == 1) y = ar[1];
            if (j == 2) y = ar[2];
            if (j == 3) y = ar[3];
            if (j == 4) y = ar[4];
            if (j == 5) y = ar[5];
            if (j == 6) y = ar[6];
            if (j == 7) y = ar[7];
            const float z  = u + y;
            const float e  = __expf(2.f * z);
            const float th = 1.f - 2.f * __builtin_amdgcn_rcpf(e + 1.f);  // tanh
            holdv = 0.5f * holdv + 0.5f * th;
            hperm[npar][permidx(myrow)] = holdv;          // own slice via LDS
            store_fast_safe(&HfN[myrow*2], holdv, want);  // sc0, THEN sc0 sc1
        }

        // ---- filler (delays first poll past the store's landing):
        //      out[b][t-1] projection emit + u_{t+1}
        op = dpp_add<0xB1>(op);  op = dpp_add<0x4E>(op);
        op = dpp_add<0x124>(op); op = dpp_add<0x128>(op);
        op = dpp_add<0x142>(op);
        if (t > 0 && ovalid && ((lane & 31) == 31))
            orow[(size_t)(t-1)*50 + oidx] = op;
        {
            const int tt = (t < 2047) ? t + 1 : 2047;
            float un = 0.f;
            #pragma unroll
            for (int k = 0; k < 25; ++k) un = fmaf(WinR[k], xrow[tt*25 + k], un);
            u = un;
        }

        // ---- comm wave: tagged fetch of 3 remote slices
        if (wv == 0) {
            const float* p0 = HfN + (s0*256 + lane*4);
            const float* p1 = HfN + (s1*256 + lane*4);
            const float* p2 = HfN + (s2*256 + lane*4);
            v4f d0, d1, d2;
            if (fast) {
                // t==0 grace: launch/preamble skew across 256 blocks can
                // exceed 64 tries; do not let it kill the sticky fast path.
                const int budget = (t == 0) ? 2048 : 64;
                int tries = 0;
                do { load3_l2(p0, p1, p2, d0, d1, d2); } while (TAGS_BAD && ++tries < budget);
                if (TAGS_BAD) fast = false;   // sticky fallback: fast path dead
            }
            if (!fast) {
                do { load3_ic(p0, p1, p2, d0, d1, d2); } while (TAGS_BAD);
            }
            const int c0 = s0*128 + 2*lane, c1 = s1*128 + 2*lane, c2 = s2*128 + 2*lane;
            hperm[npar][permidx(c0)]     = d0.x;
            hperm[npar][permidx(c0 + 1)] = d0.z;
            hperm[npar][permidx(c1)]     = d1.x;
            hperm[npar][permidx(c1 + 1)] = d1.z;
            hperm[npar][permidx(c2)]     = d2.x;
            hperm[npar][permidx(c2 + 1)] = d2.z;
        }
        __syncthreads();   // the ONLY barrier per step
    }

    // epilogue: out[b][2047] from h_2048 (in hperm[0])
    {
        float op = 0.f;
        #pragma unroll
        for (int r = 0; r < 4; ++r) {
            v4f hv = *(const v4f*)&hperm[0][r*128 + ct*4];
            #pragma unroll
            for (int q = 0; q < 4; ++q) op = fmaf(WoutR[r*4+q], hv[q], op);
        }
        op = dpp_add<0xB1>(op);  op = dpp_add<0x4E>(op);
        op = dpp_add<0x124>(op); op = dpp_add<0x128>(op);
        op = dpp_add<0x142>(op);
        if (ovalid && ((lane & 31) == 31))
            orow[(size_t)2047*50 + oidx] = op;
    }
}

extern "C" void kernel_launch(void* const* d_in, const int* in_sizes, int n_in,
                              void* d_out, int out_size, void* d_ws, size_t ws_size,
                              hipStream_t stream)
{
    (void)in_sizes; (void)n_in; (void)out_size; (void)ws_size;
    const float* x    = (const float*)d_in[0];
    const float* Win  = (const float*)d_in[1];
    const float* W    = (const float*)d_in[2];
    const float* Wout = (const float*)d_in[3];
    float* out = (float*)d_out;
    float* Hf  = (float*)d_ws;   // [2][64][512] x {h,tag} = 512 KB (same as R5)
    esn_kernel<<<dim3(256), dim3(512), 0, stream>>>(x, Win, W, Wout, out, Hf);
}

// Round 6
// 4225.870 us; speedup vs baseline: 1.3672x; 1.3672x over previous
//
#include <hip/hip_runtime.h>
#include <math.h>

// ESN: B=64, T=2048, I=25, R=512, O=50, alpha=0.5
// 256 blocks x 512 threads; block=(g,b): b=blk&63, g=blk>>6 owns rows
// [g*128,(g+1)*128). W slice [128x512] fp32 in regs. Seqlock-tagged h pairs
// {h, tag=t+1}, double-buffered by step parity.
// R14 = dedicated-storer-wave redesign of R13's goal (store drain off all
// critical paths), with NO LDS spin handoff (R13's suspected hang):
//  (1) fin lanes write h to LDS only (hperm + row-ordered hstage[128]).
//  (2) barrier#1 (lgkm-only) -> wave 7 ALONE reads hstage (ds_read_b64)
//      and publishes all 128 rows: 64x global_store_dwordx4 {h0,tag,h1,tag}
//      sc0 sc1 -- matches pollers' 16B read granularity; each 8B half is
//      self-tagged (atomicity >= the R5-proven 8B-store scheme).
//  (3) wv0 issues NO global stores ever (orow duty moved to waves 1..7 via
//      oloc=2*wv-2+hw) -> poll vmcnt(0) waits only on its own poll loads.
//  (4) lgkm-only barriers (x2/step): no vmcnt(0) store drain at barriers
//      (R12 proved stores write through to HBM, ~1400cy drain; in-order
//      vmcnt retirement makes any later wait stall on them).
//  (5) x prefetched at step top, u_next computed BEFORE any store asm, so
//      conservative compiler waits land before this step's store.
//  (6) WAW guard (parity addr reuse t vs t-2): wv7 only, vmcnt(2) at step
//      top -- free in steady state, guarantees t-2 h-store retired.
//  Unchanged, R5-proven: sc0 fast poll + 64-try watchdog (2048 at t=0) +
//  sticky sc0 sc1 IC fallback (the only unbounded loop). No new spins.
//  Deadlock-free by pipeline induction: poll(t) needs peers' barrier#1(t),
//  which needs peers' poll(t-1) done, which needed our publish(t-1) --
//  already complete before our barrier#1(t). Monotone, no cycle.
// ws usage: EXACTLY 512 KB (Hf only), layout identical to R5/R8/R10.

typedef float v2f __attribute__((ext_vector_type(2)));
typedef float v4f __attribute__((ext_vector_type(4)));

template<int CTRL>
__device__ __forceinline__ float dpp_add(float x) {
    int y = __builtin_amdgcn_update_dpp(0, __float_as_int(x), CTRL, 0xF, 0xF, false);
    return x + __int_as_float(y);
}
// 0xB1 quad_perm[1,0,3,2], 0x4E quad_perm[2,3,0,1], 0x124 row_ror:4,
// 0x128 row_ror:8, 0x142 row_bcast15

// publish 2 rows: {h0, tag, h1, tag} as one 16B sc0 sc1 store
__device__ __forceinline__ void store_ic16(float* p, float h0, float h1, int tag) {
    v4f v; v[0] = h0; v[1] = __int_as_float(tag);
    v[2] = h1; v[3] = __int_as_float(tag);
    asm volatile("global_store_dwordx4 %0, %1, off sc0 sc1"
                 :: "v"(p), "v"(v) : "memory");
}
// 3 tagged 16B loads + wait in ONE asm block (R5-proven codegen shape)
__device__ __forceinline__ void load3_ic(const float* p0, const float* p1,
                                         const float* p2, v4f& a, v4f& b, v4f& c) {
    asm volatile("global_load_dwordx4 %0, %3, off sc0 sc1\n\t"
                 "global_load_dwordx4 %1, %4, off sc0 sc1\n\t"
                 "global_load_dwordx4 %2, %5, off sc0 sc1\n\t"
                 "s_waitcnt vmcnt(0)"
                 : "=&v"(a), "=&v"(b), "=&v"(c)
                 : "v"(p0), "v"(p1), "v"(p2) : "memory");
}
__device__ __forceinline__ void load3_l2(const float* p0, const float* p1,
                                         const float* p2, v4f& a, v4f& b, v4f& c) {
    asm volatile("global_load_dwordx4 %0, %3, off sc0\n\t"
                 "global_load_dwordx4 %1, %4, off sc0\n\t"
                 "global_load_dwordx4 %2, %5, off sc0\n\t"
                 "s_waitcnt vmcnt(0)"
                 : "=&v"(a), "=&v"(b), "=&v"(c)
                 : "v"(p0), "v"(p1), "v"(p2) : "memory");
}

__device__ __forceinline__ int permidx(int c) {
    return (c >> 7) * 128 + (c & 31) * 4 + ((c >> 5) & 3);
}

#define TAGS_BAD (__any((__float_as_int(d0.y) != want) | (__float_as_int(d0.w) != want) | \
                        (__float_as_int(d1.y) != want) | (__float_as_int(d1.w) != want) | \
                        (__float_as_int(d2.y) != want) | (__float_as_int(d2.w) != want)))

// lgkm-only barrier: make LDS writes visible, do NOT drain global stores.
#define BAR_LGKM() do { \
    asm volatile("s_waitcnt lgkmcnt(0)" ::: "memory"); \
    __builtin_amdgcn_s_barrier(); } while (0)

__global__ void __launch_bounds__(512, 2)
esn_kernel(const float* __restrict__ x, const float* __restrict__ Win,
           const float* __restrict__ W, const float* __restrict__ Wout,
           float* __restrict__ out, float* __restrict__ Hf)
{
    const int b    = blockIdx.x & 63;
    const int g    = blockIdx.x >> 6;
    const int tid  = threadIdx.x;
    const int rt   = tid >> 5;      // row-tile 0..15 (8 rows each)
    const int ct   = tid & 31;      // col phase
    const int lane = tid & 63;
    const int wv   = tid >> 6;      // wave 0..7
    const int hw   = rt & 1;

    __shared__ __align__(16) float hperm[2][512];
    __shared__ __align__(8)  float hstage[128];   // row-ordered h (fin -> wv7)

    // ---- W slice -> registers
    v2f Wreg[64];
    {
        const int i0 = g*128 + rt*8;
        #pragma unroll
        for (int r = 0; r < 4; ++r)
        #pragma unroll
        for (int q = 0; q < 4; ++q) {
            const float* wp = W + (r*128 + q*32 + ct);
            #pragma unroll
            for (int p = 0; p < 4; ++p) {
                v2f w;
                w[0] = wp[(size_t)(i0 + 2*p    ) * 512];
                w[1] = wp[(size_t)(i0 + 2*p + 1) * 512];
                Wreg[(r*4+q)*4 + p] = w;
            }
        }
    }

    // ---- Win row for this lane's finalize row i0+(ct&7)
    const int myrow = g*128 + rt*8 + (ct & 7);
    float WinR[25];
    #pragma unroll
    for (int k = 0; k < 25; ++k) WinR[k] = Win[myrow*25 + k];

    // ---- Wout fragment: orow duty on waves 1..7 (wv0 must stay store-free)
    const int obase = g*13;
    const int ocnt  = (g == 3) ? 11 : 13;
    const int oloc  = 2*wv - 2 + hw;            // wv0 -> negative -> invalid
    const bool ovalid = (wv != 0) & (oloc < ocnt);
    const int oidx  = obase + (ovalid ? oloc : 0);
    float WoutR[16];
    #pragma unroll
    for (int r = 0; r < 4; ++r)
    #pragma unroll
    for (int q = 0; q < 4; ++q)
        WoutR[r*4+q] = ovalid ? Wout[oidx*512 + r*128 + q*32 + ct] : 0.f;

    hperm[0][tid] = 0.f;        // h_0 = 0
    float holdv = 0.f;
    const bool fin = (ct >= 16) & (ct < 24);

    const float* xrow = x   + (size_t)b * 2048 * 25;
    float*       orow = out + (size_t)b * 2048 * 50;
    float* HfB0 = Hf + (size_t)b * 1024;              // par-0 base (pairs)
    const int s0 = (g+1)&3, s1 = (g+2)&3, s2 = (g+3)&3;

    bool fast = true;           // sticky fast-path flag (comm wave only)

    __syncthreads();

    // u for t=0
    float u = 0.f;
    #pragma unroll
    for (int k = 0; k < 25; ++k) u = fmaf(WinR[k], xrow[k], u);

    for (int t = 0; t < 2048; ++t) {
        const int par  = t & 1;
        const int npar = par ^ 1;
        const int want = t + 1;
        float* HfN = HfB0 + (size_t)npar * 64 * 1024;

        // ---- WAW guard: only wv7 re-stores parity Hf addresses (t vs t-2).
        // vmcnt(2) is free in steady state (outstanding = t-1's <=2 stores)
        // and by in-order retirement guarantees the t-2 h-store retired.
        if (wv == 7) asm volatile("s_waitcnt vmcnt(2)" ::: "memory");

        // ---- prefetch next x row (issued before ANY store asm this step)
        float xv[25];
        {
            const int tt = (t < 2047) ? t + 1 : 2047;
            #pragma unroll
            for (int k = 0; k < 25; ++k) xv[k] = xrow[tt*25 + k];
        }

        // ---- matvec on h_t + fused output-projection partial
        v2f acc0 = {0.f,0.f}, acc1 = {0.f,0.f}, acc2 = {0.f,0.f}, acc3 = {0.f,0.f};
        float op = 0.f;
        #pragma unroll
        for (int r = 0; r < 4; ++r) {
            v4f hv = *(const v4f*)&hperm[par][r*128 + ct*4];
            #pragma unroll
            for (int q = 0; q < 4; ++q) {
                const float hs = hv[q];
                op = fmaf(WoutR[r*4+q], hs, op);
                v2f hh = {hs, hs};
                acc0 = __builtin_elementwise_fma(Wreg[(r*4+q)*4+0], hh, acc0);
                acc1 = __builtin_elementwise_fma(Wreg[(r*4+q)*4+1], hh, acc1);
                acc2 = __builtin_elementwise_fma(Wreg[(r*4+q)*4+2], hh, acc2);
                acc3 = __builtin_elementwise_fma(Wreg[(r*4+q)*4+3], hh, acc3);
            }
        }

        // ---- FULL 32-lane reduce of 8 row partials (totals land in lanes 16..31)
        float ar[8] = {acc0[0],acc0[1],acc1[0],acc1[1],acc2[0],acc2[1],acc3[0],acc3[1]};
        #pragma unroll
        for (int j = 0; j < 8; ++j) {
            ar[j] = dpp_add<0xB1>(ar[j]);
            ar[j] = dpp_add<0x4E>(ar[j]);
            ar[j] = dpp_add<0x124>(ar[j]);
            ar[j] = dpp_add<0x128>(ar[j]);
            ar[j] = dpp_add<0x142>(ar[j]);
        }

        // ---- u_{t+1} from prefetched x (before any store asm: clean waits)
        float un = 0.f;
        #pragma unroll
        for (int k = 0; k < 25; ++k) un = fmaf(WinR[k], xv[k], un);

        // ---- finalize rows i0+(ct&7) (lanes ct in [16,24)): LDS ONLY
        if (fin) {
            const int j = ct & 7;
            float y = ar[0];
            if (j == 1) y = ar[1];
            if (j == 2) y = ar[2];
            if (j == 3) y = ar[3];
            if (j == 4) y = ar[4];
            if (j == 5) y = ar[5];
            if (j == 6) y = ar[6];
            if (j == 7) y = ar[7];
            const float z  = u + y;
            const float e  = __expf(2.f * z);
            const float th = 1.f - 2.f * __builtin_amdgcn_rcpf(e + 1.f);  // tanh
            holdv = 0.5f * holdv + 0.5f * th;
            hperm[npar][permidx(myrow)] = holdv;      // own slice, perm layout
            hstage[rt*8 + (ct & 7)]     = holdv;      // row-ordered for wv7
        }
        u = un;

        // ---- barrier #1: fin LDS writes visible to wave 7
        BAR_LGKM();

        // ---- wave 7: publish ALL 128 rows (2 rows per lane, one 16B store)
        if (wv == 7) {
            const float h0 = hstage[2*lane];
            const float h1 = hstage[2*lane + 1];
            store_ic16(&HfN[(size_t)(g*128 + 2*lane)*2], h0, h1, want);
        }

        // ---- comm wave (wv0): tagged fetch of 3 remote slices (clean vmcnt)
        if (wv == 0) {
            const float* p0 = HfN + (s0*256 + lane*4);
            const float* p1 = HfN + (s1*256 + lane*4);
            const float* p2 = HfN + (s2*256 + lane*4);
            v4f d0, d1, d2;
            if (fast) {
                // t==0 grace: launch/preamble skew can exceed 64 tries.
                const int budget = (t == 0) ? 2048 : 64;
                int tries = 0;
                do { load3_l2(p0, p1, p2, d0, d1, d2); } while (TAGS_BAD && ++tries < budget);
                if (TAGS_BAD) fast = false;   // sticky fallback: fast path dead
            }
            if (!fast) {
                do { load3_ic(p0, p1, p2, d0, d1, d2); } while (TAGS_BAD);
            }
            const int c0 = s0*128 + 2*lane, c1 = s1*128 + 2*lane, c2 = s2*128 + 2*lane;
            hperm[npar][permidx(c0)]     = d0.x;
            hperm[npar][permidx(c0 + 1)] = d0.z;
            hperm[npar][permidx(c1)]     = d1.x;
            hperm[npar][permidx(c1 + 1)] = d1.z;
            hperm[npar][permidx(c2)]     = d2.x;
            hperm[npar][permidx(c2 + 1)] = d2.z;
        }

        // ---- output projection emit for t-1 (waves 1..7; plain stores)
        op = dpp_add<0xB1>(op);  op = dpp_add<0x4E>(op);
        op = dpp_add<0x124>(op); op = dpp_add<0x128>(op);
        op = dpp_add<0x142>(op);
        if (t > 0 && ovalid && ((lane & 31) == 31))
            orow[(size_t)(t-1)*50 + oidx] = op;

        // ---- barrier #2: poll writes visible; no global-store drain
        BAR_LGKM();
    }

    // epilogue: out[b][2047] from h_2048 (in hperm[0])
    {
        float op = 0.f;
        #pragma unroll
        for (int r = 0; r < 4; ++r) {
            v4f hv = *(const v4f*)&hperm[0][r*128 + ct*4];
            #pragma unroll
            for (int q = 0; q < 4; ++q) op = fmaf(WoutR[r*4+q], hv[q], op);
        }
        op = dpp_add<0xB1>(op);  op = dpp_add<0x4E>(op);
        op = dpp_add<0x124>(op); op = dpp_add<0x128>(op);
        op = dpp_add<0x142>(op);
        if (ovalid && ((lane & 31) == 31))
            orow[(size_t)2047*50 + oidx] = op;
    }
}

extern "C" void kernel_launch(void* const* d_in, const int* in_sizes, int n_in,
                              void* d_out, int out_size, void* d_ws, size_t ws_size,
                              hipStream_t stream)
{
    (void)in_sizes; (void)n_in; (void)out_size; (void)ws_size;
    const float* x    = (const float*)d_in[0];
    const float* Win  = (const float*)d_in[1];
    const float* W    = (const float*)d_in[2];
    const float* Wout = (const float*)d_in[3];
    float* out = (float*)d_out;
    float* Hf  = (float*)d_ws;   // [2][64][512] x {h,tag} = 512 KB (same as R5)
    esn_kernel<<<dim3(256), dim3(512), 0, stream>>>(x, Win, W, Wout, out, Hf);
}

// Round 7
// 4208.631 us; speedup vs baseline: 1.3728x; 1.0041x over previous
//
#include <hip/hip_runtime.h>
#include <math.h>

// ESN: B=64, T=2048, I=25, R=512, O=50, alpha=0.5
// 256 blocks x 512 threads; block=(g,b): b=blk&63, g=blk>>6 owns rows
// [g*128,(g+1)*128). W slice [128x512] fp32 in regs. Seqlock-tagged h pairs
// {h, tag=t+1} (8B single-copy atomic), double-buffered by step parity.
// R15 = R10 publish timing + ALL THREE store-drain exposures removed.
//  Facts: stores write through to HBM (~1400cy drain; R12 doubled WRITE and
//  +3400cy/step); vmcnt retires IN ORDER so any later wait drains them;
//  delaying publish behind a barrier costs more than the drain (R14).
//  (1) u_next early from step-top-prefetched x (R14-proven): the x-load
//      wait lands BEFORE this step's fin store, not after.
//  (2) lgkm-only barrier (raw s_barrier + lgkmcnt(0), R14-proven): no
//      vmcnt(0) store drain at the barrier. WAW guard at step top per wave
//      (vmcnt(S), S = that wave's stores/step; in-order retirement =>
//      t-2's same-address fin store retired). Free in steady state.
//  (3) wv0 issues its 3 poll loads BEFORE its fin store, waits vmcnt(1):
//      the 3 OLDER loads complete; the YOUNGER store may stay in flight.
//      Publish timing identical to R10; poll no longer drains own store.
//      R11's miscompile avoided structurally: d0..d2 declared + defined
//      (unconditionally) + waited ("+v") + consumed inside ONE wave-uniform
//      if(wv==0) block; sched_barrier(0) after the wait (guide rule #18);
//      no loads/uses between issue and wait so no compiler waitcnt there.
//  orow duty on waves 1..7 only (R14 mapping). Watchdog + t0-grace +
//  sticky sc0->sc0sc1 fallback UNCHANGED (R5-proven hang-free). Every
//  block publishes unconditionally every step -> no circular wait.
// ws usage: EXACTLY 512 KB (Hf only), layout identical to R5/R8/R10.

typedef float v2f __attribute__((ext_vector_type(2)));
typedef float v4f __attribute__((ext_vector_type(4)));

template<int CTRL>
__device__ __forceinline__ float dpp_add(float x) {
    int y = __builtin_amdgcn_update_dpp(0, __float_as_int(x), CTRL, 0xF, 0xF, false);
    return x + __int_as_float(y);
}
// 0xB1 quad_perm[1,0,3,2], 0x4E quad_perm[2,3,0,1], 0x124 row_ror:4,
// 0x128 row_ror:8, 0x142 row_bcast15

__device__ __forceinline__ void store_ic8(float* p, float h, int tag) {
    v2f v; v[0] = h; v[1] = __int_as_float(tag);
    asm volatile("global_store_dwordx2 %0, %1, off sc0 sc1"
                 :: "v"(p), "v"(v) : "memory");
}
// 3 tagged 16B loads + wait in ONE asm block (R5-proven codegen shape)
__device__ __forceinline__ void load3_ic(const float* p0, const float* p1,
                                         const float* p2, v4f& a, v4f& b, v4f& c) {
    asm volatile("global_load_dwordx4 %0, %3, off sc0 sc1\n\t"
                 "global_load_dwordx4 %1, %4, off sc0 sc1\n\t"
                 "global_load_dwordx4 %2, %5, off sc0 sc1\n\t"
                 "s_waitcnt vmcnt(0)"
                 : "=&v"(a), "=&v"(b), "=&v"(c)
                 : "v"(p0), "v"(p1), "v"(p2) : "memory");
}
__device__ __forceinline__ void load3_l2(const float* p0, const float* p1,
                                         const float* p2, v4f& a, v4f& b, v4f& c) {
    asm volatile("global_load_dwordx4 %0, %3, off sc0\n\t"
                 "global_load_dwordx4 %1, %4, off sc0\n\t"
                 "global_load_dwordx4 %2, %5, off sc0\n\t"
                 "s_waitcnt vmcnt(0)"
                 : "=&v"(a), "=&v"(b), "=&v"(c)
                 : "v"(p0), "v"(p1), "v"(p2) : "memory");
}
// issue-only speculative poll; dest regs live ONLY within the wv0 block
__device__ __forceinline__ void load3_l2_issue(const float* p0, const float* p1,
                                               const float* p2, v4f& a, v4f& b, v4f& c) {
    asm volatile("global_load_dwordx4 %0, %3, off sc0\n\t"
                 "global_load_dwordx4 %1, %4, off sc0\n\t"
                 "global_load_dwordx4 %2, %5, off sc0"
                 : "=&v"(a), "=&v"(b), "=&v"(c)
                 : "v"(p0), "v"(p1), "v"(p2) : "memory");
}
// wait for the 3 older poll loads; own (younger) fin store may stay in flight
__device__ __forceinline__ void wait_vm1(v4f& a, v4f& b, v4f& c) {
    asm volatile("s_waitcnt vmcnt(1)"
                 : "+v"(a), "+v"(b), "+v"(c) :: "memory");
    __builtin_amdgcn_sched_barrier(0);   // rule #18: pin uses after the wait
}

__device__ __forceinline__ int permidx(int c) {
    return (c >> 7) * 128 + (c & 31) * 4 + ((c >> 5) & 3);
}

#define TAGS_BAD (__any((__float_as_int(d0.y) != want) | (__float_as_int(d0.w) != want) | \
                        (__float_as_int(d1.y) != want) | (__float_as_int(d1.w) != want) | \
                        (__float_as_int(d2.y) != want) | (__float_as_int(d2.w) != want)))

// lgkm-only barrier: make LDS writes visible, do NOT drain global stores.
#define BAR_LGKM() do { \
    asm volatile("s_waitcnt lgkmcnt(0)" ::: "memory"); \
    __builtin_amdgcn_s_barrier(); } while (0)

__global__ void __launch_bounds__(512, 2)
esn_kernel(const float* __restrict__ x, const float* __restrict__ Win,
           const float* __restrict__ W, const float* __restrict__ Wout,
           float* __restrict__ out, float* __restrict__ Hf)
{
    const int b    = blockIdx.x & 63;
    const int g    = blockIdx.x >> 6;
    const int tid  = threadIdx.x;
    const int rt   = tid >> 5;      // row-tile 0..15 (8 rows each)
    const int ct   = tid & 31;      // col phase
    const int lane = tid & 63;
    const int wv   = tid >> 6;      // wave 0..7
    const int hw   = rt & 1;

    __shared__ __align__(16) float hperm[2][512];

    // ---- W slice -> registers
    v2f Wreg[64];
    {
        const int i0 = g*128 + rt*8;
        #pragma unroll
        for (int r = 0; r < 4; ++r)
        #pragma unroll
        for (int q = 0; q < 4; ++q) {
            const float* wp = W + (r*128 + q*32 + ct);
            #pragma unroll
            for (int p = 0; p < 4; ++p) {
                v2f w;
                w[0] = wp[(size_t)(i0 + 2*p    ) * 512];
                w[1] = wp[(size_t)(i0 + 2*p + 1) * 512];
                Wreg[(r*4+q)*4 + p] = w;
            }
        }
    }

    // ---- Win row for this lane's finalize row i0+(ct&7)
    const int myrow  = g*128 + rt*8 + (ct & 7);
    const int pmyrow = permidx(myrow);
    float WinR[25];
    #pragma unroll
    for (int k = 0; k < 25; ++k) WinR[k] = Win[myrow*25 + k];

    // ---- Wout fragment: orow duty on waves 1..7 (wv0 must stay clean)
    const int obase = g*13;
    const int ocnt  = (g == 3) ? 11 : 13;
    const int oloc  = 2*wv - 2 + hw;            // wv0 -> negative -> invalid
    const bool ovalid = (wv != 0) & (oloc >= 0) & (oloc < ocnt);
    const int oidx  = obase + (ovalid ? oloc : 0);
    float WoutR[16];
    #pragma unroll
    for (int r = 0; r < 4; ++r)
    #pragma unroll
    for (int q = 0; q < 4; ++q)
        WoutR[r*4+q] = ovalid ? Wout[oidx*512 + r*128 + q*32 + ct] : 0.f;

    hperm[0][tid] = 0.f;        // h_0 = 0
    float holdv = 0.f;
    const bool fin = (ct >= 16) & (ct < 24);

    const float* xrow = x   + (size_t)b * 2048 * 25;
    float*       orow = out + (size_t)b * 2048 * 50;
    float* HfB0 = Hf + (size_t)b * 1024;              // par-0 base (pairs)
    const int s0 = (g+1)&3, s1 = (g+2)&3, s2 = (g+3)&3;

    bool fast = true;           // sticky fast-path flag (comm wave only)

    __syncthreads();

    // u for t=0
    float u = 0.f;
    #pragma unroll
    for (int k = 0; k < 25; ++k) u = fmaf(WinR[k], xrow[k], u);

    for (int t = 0; t < 2048; ++t) {
        const int par  = t & 1;
        const int npar = par ^ 1;
        const int want = t + 1;
        float* HfN = HfB0 + (size_t)npar * 64 * 1024;

        // ---- WAW guard (waves 1..7; free in steady state): by in-order
        // retirement, <=S outstanding means this wave's t-2 stores retired
        // before we re-store the same parity addresses this step.
        // S = stores/step: fin + orow = 2, except (g==3, wv==7): fin only.
        if (wv != 0) {
            if (g == 3 && wv == 7) asm volatile("s_waitcnt vmcnt(1)" ::: "memory");
            else                   asm volatile("s_waitcnt vmcnt(2)" ::: "memory");
        }

        // ---- prefetch next x row (consumed by u_next BEFORE any store)
        float xv[25];
        {
            const int tt = (t < 2047) ? t + 1 : 2047;
            #pragma unroll
            for (int k = 0; k < 25; ++k) xv[k] = xrow[tt*25 + k];
        }

        // ---- matvec on h_t + fused output-projection partial
        v2f acc0 = {0.f,0.f}, acc1 = {0.f,0.f}, acc2 = {0.f,0.f}, acc3 = {0.f,0.f};
        float op = 0.f;
        #pragma unroll
        for (int r = 0; r < 4; ++r) {
            v4f hv = *(const v4f*)&hperm[par][r*128 + ct*4];
            #pragma unroll
            for (int q = 0; q < 4; ++q) {
                const float hs = hv[q];
                op = fmaf(WoutR[r*4+q], hs, op);
                v2f hh = {hs, hs};
                acc0 = __builtin_elementwise_fma(Wreg[(r*4+q)*4+0], hh, acc0);
                acc1 = __builtin_elementwise_fma(Wreg[(r*4+q)*4+1], hh, acc1);
                acc2 = __builtin_elementwise_fma(Wreg[(r*4+q)*4+2], hh, acc2);
                acc3 = __builtin_elementwise_fma(Wreg[(r*4+q)*4+3], hh, acc3);
            }
        }

        // ---- FULL 32-lane reduce of 8 row partials (totals land in lanes 16..31)
        float ar[8] = {acc0[0],acc0[1],acc1[0],acc1[1],acc2[0],acc2[1],acc3[0],acc3[1]};
        #pragma unroll
        for (int j = 0; j < 8; ++j) {
            ar[j] = dpp_add<0xB1>(ar[j]);
            ar[j] = dpp_add<0x4E>(ar[j]);
            ar[j] = dpp_add<0x124>(ar[j]);
            ar[j] = dpp_add<0x128>(ar[j]);
            ar[j] = dpp_add<0x142>(ar[j]);
        }

        // ---- u_{t+1} from prefetched x: its load-wait lands HERE, before
        // this step's fin store (drain exposure #1 removed).
        float un = 0.f;
        #pragma unroll
        for (int k = 0; k < 25; ++k) un = fmaf(WinR[k], xv[k], un);

        // ---- finalize rows i0+(ct&7) (lanes ct in [16,24)): holdv + LDS
        if (fin) {
            const int j = ct & 7;
            float y = ar[0];
            if (j == 1) y = ar[1];
            if (j == 2) y = ar[2];
            if (j == 3) y = ar[3];
            if (j == 4) y = ar[4];
            if (j == 5) y = ar[5];
            if (j == 6) y = ar[6];
            if (j == 7) y = ar[7];
            const float z  = u + y;
            const float e  = __expf(2.f * z);
            const float th = 1.f - 2.f * __builtin_amdgcn_rcpf(e + 1.f);  // tanh
            holdv = 0.5f * holdv + 0.5f * th;
            hperm[npar][pmyrow] = holdv;              // own slice via LDS
        }
        u = un;

        if (wv == 0) {
            // ---- comm wave: poll loads FIRST (older), own fin store
            // SECOND (younger). wait vmcnt(1) completes the loads while
            // the store may stay in flight (drain exposure #3 removed).
            const float* p0 = HfN + (s0*256 + lane*4);
            const float* p1 = HfN + (s1*256 + lane*4);
            const float* p2 = HfN + (s2*256 + lane*4);
            v4f d0, d1, d2;
            load3_l2_issue(p0, p1, p2, d0, d1, d2);
            if (fin) store_ic8(&HfN[myrow*2], holdv, want);   // publish NOW
            wait_vm1(d0, d1, d2);
            if (fast) {
                // t==0 grace: launch/preamble skew can exceed 64 tries.
                const int budget = (t == 0) ? 2048 : 64;
                int tries = 0;
                while (TAGS_BAD && ++tries < budget)
                    load3_l2(p0, p1, p2, d0, d1, d2);
                if (TAGS_BAD) fast = false;   // sticky fallback: fast path dead
            }
            if (!fast) {
                do { load3_ic(p0, p1, p2, d0, d1, d2); } while (TAGS_BAD);
            }
            const int c0 = s0*128 + 2*lane, c1 = s1*128 + 2*lane, c2 = s2*128 + 2*lane;
            hperm[npar][permidx(c0)]     = d0.x;
            hperm[npar][permidx(c0 + 1)] = d0.z;
            hperm[npar][permidx(c1)]     = d1.x;
            hperm[npar][permidx(c1 + 1)] = d1.z;
            hperm[npar][permidx(c2)]     = d2.x;
            hperm[npar][permidx(c2 + 1)] = d2.z;
        } else {
            // ---- waves 1..7: publish immediately (R10 timing), then the
            // output-projection emit for t-1 (fire-and-forget stores).
            if (fin) store_ic8(&HfN[myrow*2], holdv, want);
            op = dpp_add<0xB1>(op);  op = dpp_add<0x4E>(op);
            op = dpp_add<0x124>(op); op = dpp_add<0x128>(op);
            op = dpp_add<0x142>(op);
            if (t > 0 && ovalid && ((lane & 31) == 31))
                orow[(size_t)(t-1)*50 + oidx] = op;
        }

        // ---- lgkm-only barrier: no global-store drain (exposure #2 removed)
        BAR_LGKM();
    }

    // epilogue: out[b][2047] from h_2048 (in hperm[0])
    {
        float op = 0.f;
        #pragma unroll
        for (int r = 0; r < 4; ++r) {
            v4f hv = *(const v4f*)&hperm[0][r*128 + ct*4];
            #pragma unroll
            for (int q = 0; q < 4; ++q) op = fmaf(WoutR[r*4+q], hv[q], op);
        }
        op = dpp_add<0xB1>(op);  op = dpp_add<0x4E>(op);
        op = dpp_add<0x124>(op); op = dpp_add<0x128>(op);
        op = dpp_add<0x142>(op);
        if (ovalid && ((lane & 31) == 31))
            orow[(size_t)2047*50 + oidx] = op;
    }
}

extern "C" void kernel_launch(void* const* d_in, const int* in_sizes, int n_in,
                              void* d_out, int out_size, void* d_ws, size_t ws_size,
                              hipStream_t stream)
{
    (void)in_sizes; (void)n_in; (void)out_size; (void)ws_size;
    const float* x    = (const float*)d_in[0];
    const float* Win  = (const float*)d_in[1];
    const float* W    = (const float*)d_in[2];
    const float* Wout = (const float*)d_in[3];
    float* out = (float*)d_out;
    float* Hf  = (float*)d_ws;   // [2][64][512] x {h,tag} = 512 KB (same as R5)
    esn_kernel<<<dim3(256), dim3(512), 0, stream>>>(x, Win, W, Wout, out, Hf);
}